// Round 21
// baseline (5832.912 us; speedup 1.0000x reference)
//
#include <hip/hip_runtime.h>
#include <math.h>

#define DD 64
#define NSWEEP 7

typedef float f32x2 __attribute__((ext_vector_type(2)));

__device__ __forceinline__ float rdlane(float v, int l) {
    return __int_as_float(__builtin_amdgcn_readlane(__float_as_int(v), l));
}
__device__ __forceinline__ float bperm(int paddr, float v) {
    return __int_as_float(__builtin_amdgcn_ds_bpermute(paddr, __float_as_int(v)));
}

// ---------------- Kernel 1: split-column one-sided Jacobi ----------------
// Round-20 model (validated to 1%): remat = 129 DS-ops/stage x 3.6cyc = the
// entire 5.5ms. Fix: 2 waves per matrix, wave h holds elements [32h,32h+32)
// of column `lane`. w2[16]+oth2[16]=64 regs BOTH live -> no remat: 32 bperm
// + 1 noth + 2 LDS ops per wave per stage (~70/matrix vs 129). Cross-wave
// dot combine via parity-double-buffered LDS + 1 barrier/stage (write[g&1],
// barrier, read; same slot rewritten 2 barriers later -> WAR-safe, incl.
// across sweep boundaries via running counter g). Both waves duplicate the
// Cholesky (identical readlane arithmetic) to avoid a layout transfer.
__global__ __launch_bounds__(128, 2)
void logeig_sweeps_kernel(const float* __restrict__ X, float* __restrict__ Wout, int nb) {
    __shared__ float hd[2][2][DD];   // [parity][wave][lane] half-dot exchange
    __shared__ float hn[2][DD];      // one-time half-norm exchange

    const int b = blockIdx.x;
    if (b >= nb) return;
    const int tid  = threadIdx.x;
    const int lane = tid & 63;
    const int h    = tid >> 6;       // which half of the column this wave holds
    const float* Xb = X + (size_t)b * DD * DD;

    // Full-column symmetrize + Cholesky, duplicated in both waves (identical
    // register state -> identical results; no cross-wave transfer needed).
    float w[DD];
    #pragma unroll
    for (int e = 0; e < DD; ++e)
        w[e] = 0.5f * (Xb[e * DD + lane] + Xb[lane * DD + e]);

    #pragma unroll
    for (int k = 0; k < DD; ++k) {
        const float pivot = rdlane(w[k], k);
        const float rinv  = 1.0f / sqrtf(pivot);
        const float ljk   = w[k] * rinv;
        const bool  gtk   = (lane > k);
        const bool  eqk   = (lane == k);
        #pragma unroll
        for (int e = k; e < DD; ++e) {
            const float lek = rdlane(w[e], k) * rinv;
            const float upd = fmaf(-lek, ljk, w[e]);
            w[e] = eqk ? lek : (gtk ? upd : w[e]);
        }
    }
    #pragma unroll
    for (int e = 0; e < DD - 1; ++e)
        if (e < lane) w[e] = 0.0f;

    // Keep only this wave's half, packed (w[] dies here; pressure drops).
    f32x2 w2[16];
    #pragma unroll
    for (int i = 0; i < 16; ++i) {
        w2[i].x = w[h * 32 + 2 * i];
        w2[i].y = w[h * 32 + 2 * i + 1];
    }

    // Initial norm: half-norms through LDS, same add order in both waves.
    {
        f32x2 a0 = {0.f, 0.f}, a1 = {0.f, 0.f};
        #pragma unroll
        for (int i = 0; i < 16; i += 2) {
            a0 = w2[i] * w2[i] + a0;
            a1 = w2[i + 1] * w2[i + 1] + a1;
        }
        hn[h][lane] = (a0.x + a0.y) + (a1.x + a1.y);
    }
    __syncthreads();
    float nown = hn[0][lane] + hn[1][lane];

    const int lane4 = lane << 2;
    int g = 0;                        // running stage counter (parity)

    for (int sw = 0; sw < NSWEEP; ++sw) {
        bool sweep_rotated = false;
        for (int m = 1; m < DD; ++m, ++g) {
            const int paddr = lane4 ^ (m << 2);   // partner*4 (XOR pairing)
            const int par   = g & 1;

            // In-wave exchange of this half: 32 b32 bperms, oth2 fully live.
            f32x2 oth2[16];
            #pragma unroll
            for (int i = 0; i < 16; ++i) {
                oth2[i].x = bperm(paddr, w2[i].x);
                oth2[i].y = bperm(paddr, w2[i].y);
            }

            // Half-dot (identical expression in both lanes of a pair).
            f32x2 dv0 = {0.f, 0.f}, dv1 = {0.f, 0.f};
            #pragma unroll
            for (int i = 0; i < 16; i += 2) {
                dv0 = w2[i] * oth2[i] + dv0;
                dv1 = w2[i + 1] * oth2[i + 1] + dv1;
            }
            hd[par][h][lane] = (dv0.x + dv0.y) + (dv1.x + dv1.y);
            const float noth = bperm(paddr, nown);
            __syncthreads();
            const float d = hd[par][0][lane] + hd[par][1][lane];

            // Relative tol 1e-4 (absmax-neutral, rounds 9-20).
            const bool dorot = (d * d > 1e-8f * nown * noth);
            if (__any(dorot)) {   // identical across both waves of the block
                sweep_rotated = true;
                const bool  islo = (paddr > lane4);   // low lane plays p
                const float app  = islo ? nown : noth;
                const float aqq  = islo ? noth : nown;
                float tau = (aqq - app) * 0.5f / d;
                float t   = 1.0f / (fabsf(tau) + sqrtf(fmaf(tau, tau, 1.0f)));
                t = copysignf(t, tau);
                float c = 1.0f / sqrtf(fmaf(t, t, 1.0f));
                float s = t * c;
                float tsgn = islo ? -t : t;           // nown' = nown -+ t*d
                if (!islo) s = -s;
                if (!dorot) { c = 1.0f; s = 0.0f; tsgn = 0.0f; }
                nown = fmaf(tsgn, d, nown);

                const f32x2 c2 = {c, c};
                const f32x2 s2 = {s, s};
                #pragma unroll
                for (int i = 0; i < 16; ++i)
                    w2[i] = c2 * w2[i] - s2 * oth2[i];
            }
        }
        if (!sweep_rotated) break;   // uniform across the block
    }

    // Stash this wave's half of W into d_out (coalesced).
    float* Wb = Wout + (size_t)b * DD * DD;
    #pragma unroll
    for (int i = 0; i < 16; ++i) {
        Wb[(h * 32 + 2 * i) * DD + lane]     = w2[i].x;
        Wb[(h * 32 + 2 * i + 1) * DD + lane] = w2[i].y;
    }
}

// ---------------- Kernel 2: epilogue out = W diag(scl) W^T (in place) --------
__global__ __launch_bounds__(256, 2)
void logeig_epilogue_kernel(float* __restrict__ out, int nb) {
    __shared__ float M[DD][DD + 1];
    __shared__ float sc[DD];

    const int b = blockIdx.x;
    if (b >= nb) return;
    const int tid  = threadIdx.x;
    const int lane = tid & 63;
    const int w4   = tid >> 6;
    float* Ob = out + (size_t)b * DD * DD;

    #pragma unroll
    for (int ii = 0; ii < 16; ++ii) {
        int r = w4 * 16 + ii;
        M[r][lane] = Ob[r * DD + lane];
    }
    __syncthreads();

    if (tid < DD) {
        float n0 = 0.f, n1 = 0.f;
        #pragma unroll
        for (int e = 0; e < DD; e += 2) {
            n0 = fmaf(M[e][tid],     M[e][tid],     n0);
            n1 = fmaf(M[e + 1][tid], M[e + 1][tid], n1);
        }
        const float nn = n0 + n1;                    // lambda_j
        sc[tid] = logf(fmaxf(nn, 1e-7f)) / nn;       // log(clip(lam))/lam
    }
    __syncthreads();

    float vrow[DD];
    #pragma unroll
    for (int j = 0; j < DD; ++j) vrow[j] = M[lane][j] * sc[j];

    float acc[16];
    #pragma unroll
    for (int ii = 0; ii < 16; ++ii) acc[ii] = 0.0f;

    for (int k = 0; k < DD; ++k) {
        const float vl = vrow[k];
        #pragma unroll
        for (int ii = 0; ii < 16; ++ii)
            acc[ii] = fmaf(M[w4 * 16 + ii][k], vl, acc[ii]);   // broadcast reads
    }

    __syncthreads();   // all reads of W done before overwriting
    #pragma unroll
    for (int ii = 0; ii < 16; ++ii)
        Ob[(size_t)(w4 * 16 + ii) * DD + lane] = acc[ii];
}

extern "C" void kernel_launch(void* const* d_in, const int* in_sizes, int n_in,
                              void* d_out, int out_size, void* d_ws, size_t ws_size,
                              hipStream_t stream) {
    (void)n_in; (void)d_ws; (void)ws_size; (void)out_size;
    const float* X = (const float*)d_in[0];
    float* out = (float*)d_out;
    int nb = in_sizes[0] / (DD * DD);
    hipLaunchKernelGGL(logeig_sweeps_kernel, dim3(nb), dim3(128), 0, stream, X, out, nb);
    hipLaunchKernelGGL(logeig_epilogue_kernel, dim3(nb), dim3(256), 0, stream, out, nb);
}